// Round 13
// baseline (304.673 us; speedup 1.0000x reference)
//
#include <hip/hip_runtime.h>
#include <hip/hip_fp16.h>
#include <math.h>

#define HDIM 128
#define LN_EPS 1e-5f
#define NCOH 8  // XCD cohorts (blockIdx % 8 ~ XCD round-robin heuristic; perf-only)

typedef _Float16 half8 __attribute__((ext_vector_type(8)));
typedef float f32x4 __attribute__((ext_vector_type(4)));

// h'[v] = dinv[v]*h[v]; agg[v] = dinv[v]*(sum_{s in N(v)} h'[s] + h'[v]).
// CSR is cohort-sharded x-major (kills fill write-amplification). agg: 4 nodes
// per wave, 16B/lane uint4 gathers (1 instr = 1 row), 16-deep => 64 rows in
// flight per wave.

// ---------------- CSR build ----------------

__global__ void count_kernel(const int* __restrict__ dst, int* __restrict__ counts8,
                             int E, int n) {
  int e = blockIdx.x * blockDim.x + threadIdx.x;
  int x = blockIdx.x & (NCOH - 1);
  if (e < E) atomicAdd(&counts8[x * n + dst[e]], 1);
}

__global__ void dinv_kernel(const int* __restrict__ counts8, float* __restrict__ dinv, int n) {
  int i = blockIdx.x * 256 + threadIdx.x;
  if (i < n) {
    int s = 0;
#pragma unroll
    for (int x = 0; x < NCOH; ++x) s += counts8[x * n + i];
    dinv[i] = rsqrtf((float)(s + 1));  // +1 self-loop
  }
}

__global__ __launch_bounds__(256) void scan_sum_kernel(const int* __restrict__ in,
                                                       int* __restrict__ blocksum, int n) {
  int base = blockIdx.x * 2048;
  int tid = threadIdx.x;
  int sum = 0;
#pragma unroll
  for (int j = 0; j < 8; ++j) {
    int i = base + tid * 8 + j;
    if (i < n) sum += in[i];
  }
#pragma unroll
  for (int off = 32; off >= 1; off >>= 1) sum += __shfl_xor(sum, off, 64);
  __shared__ int wsum[4];
  if ((tid & 63) == 0) wsum[tid >> 6] = sum;
  __syncthreads();
  if (tid == 0) blocksum[blockIdx.x] = wsum[0] + wsum[1] + wsum[2] + wsum[3];
}

__global__ __launch_bounds__(256) void scan2_kernel(int* __restrict__ blocksum, int nblk) {
  __shared__ int sh[256];
  int tid = threadIdx.x;
  sh[tid] = (tid < nblk) ? blocksum[tid] : 0;
  __syncthreads();
  for (int off = 1; off < 256; off <<= 1) {
    int t = (tid >= off) ? sh[tid - off] : 0;
    __syncthreads();
    sh[tid] += t;
    __syncthreads();
  }
  if (tid < nblk) blocksum[tid] = sh[tid];  // inclusive
}

__global__ __launch_bounds__(256) void scan_emit_kernel(const int* __restrict__ in,
                                                        const int* __restrict__ blocksum,
                                                        int* __restrict__ rowptr8,
                                                        int* __restrict__ cursor8, int n, int nblk) {
  int base = blockIdx.x * 2048;
  int tid = threadIdx.x;
  int c[8];
  int s = 0;
#pragma unroll
  for (int j = 0; j < 8; ++j) {
    int i = base + tid * 8 + j;
    c[j] = (i < n) ? in[i] : 0;
    s += c[j];
  }
  int lane = tid & 63, wid = tid >> 6;
  int incl = s;
#pragma unroll
  for (int off = 1; off < 64; off <<= 1) {
    int t = __shfl_up(incl, off, 64);
    if (lane >= off) incl += t;
  }
  __shared__ int wsum[4];
  if (lane == 63) wsum[wid] = incl;
  __syncthreads();
  int woff = 0;
  for (int w = 0; w < wid; ++w) woff += wsum[w];
  int p = (blockIdx.x == 0 ? 0 : blocksum[blockIdx.x - 1]) + woff + (incl - s);
#pragma unroll
  for (int j = 0; j < 8; ++j) {
    int i = base + tid * 8 + j;
    if (i < n) {
      rowptr8[i] = p;
      cursor8[i] = p;
    }
    p += c[j];
  }
  if (blockIdx.x == nblk - 1 && tid == 255) rowptr8[n] = blocksum[nblk - 1];
}

__global__ void fill_kernel(const int* __restrict__ src, const int* __restrict__ dst,
                            int* __restrict__ cursor8, int* __restrict__ csr8, int E, int n) {
  int e = blockIdx.x * blockDim.x + threadIdx.x;
  int x = blockIdx.x & (NCOH - 1);
  if (e < E) {
    int pos = atomicAdd(&cursor8[x * n + dst[e]], 1);
    csr8[pos] = src[e];  // cohort-owned contiguous region -> XCD-local L2 lines
  }
}

// ---------------- Prep: xs (stride 8) = dinv*x ; fp16-transposed weights ----------------

__global__ void prep_kernel(const float* __restrict__ x, const float* __restrict__ dinv,
                            float* __restrict__ xs, const float* __restrict__ W2,
                            const float* __restrict__ W3, const float* __restrict__ rW1,
                            __half* __restrict__ w2t, __half* __restrict__ w3t,
                            __half* __restrict__ rw1t, int n) {
  int idx = blockIdx.x * 256 + threadIdx.x;
  int nx = n * 8;
  if (idx < nx) {
    int vv = idx >> 3, j = idx & 7;
    xs[idx] = (j < 6) ? x[vv * 6 + j] * dinv[vv] : 0.f;
    return;
  }
  int i = idx - nx;
  if (i < 16384) {
    int nn = i >> 7, k = i & 127;
    w2t[i] = __float2half(W2[k * 128 + nn]);
  } else if (i < 32768) {
    int j = i - 16384;
    int nn = j >> 7, k = j & 127;
    w3t[j] = __float2half(W3[k * 128 + nn]);
  } else if (i < 40960) {
    int j = i - 32768;
    int nn = j >> 7, k = j & 127;
    rw1t[j] = __float2half(rW1[k * 64 + nn]);
  }
}

// ---------------- Layer 1: one wave/node; lane-owned edges, 2x float4 loads ----------

__global__ __launch_bounds__(256) void layer1_kernel(
    const float* __restrict__ xs, const float* __restrict__ W1,
    const float* __restrict__ b1, const float* __restrict__ gam,
    const float* __restrict__ bet, const int* __restrict__ rowptr8,
    const int* __restrict__ csr8, const float* __restrict__ dinv,
    __half* __restrict__ hout, int n) {
  int v = blockIdx.x * 4 + (threadIdx.x >> 6);
  if (v >= n) return;
  int lane = threadIdx.x & 63;
  int sx = 0, ex = 0;
  if (lane < NCOH) {
    sx = rowptr8[lane * n + v];
    ex = rowptr8[lane * n + v + 1];
  }
  int starts[NCOH], L[NCOH + 1];
  L[0] = 0;
#pragma unroll
  for (int u = 0; u < NCOH; ++u) {
    starts[u] = __shfl(sx, u, 64);
    L[u + 1] = L[u] + (__shfl(ex, u, 64) - starts[u]);
  }
  int deg = L[NCOH];
  float a[6] = {0.f, 0.f, 0.f, 0.f, 0.f, 0.f};
  for (int c0 = 0; c0 < deg; c0 += 64) {
    int p = c0 + lane;
    if (p < deg) {
      int u = 0;
#pragma unroll
      for (int t = 1; t < NCOH; ++t) u += (p >= L[t]);
      int s = csr8[starts[u] + (p - L[u])];  // lane-owned edge
      float4 x0 = *(const float4*)&xs[s * 8];
      float4 x1 = *(const float4*)&xs[s * 8 + 4];
      a[0] += x0.x; a[1] += x0.y; a[2] += x0.z;
      a[3] += x0.w; a[4] += x1.x; a[5] += x1.y;
    }
  }
  if (lane == 0) {
#pragma unroll
    for (int j = 0; j < 6; ++j) a[j] += xs[v * 8 + j];  // self-loop
  }
#pragma unroll
  for (int off = 32; off >= 1; off >>= 1) {
#pragma unroll
    for (int j = 0; j < 6; ++j) a[j] += __shfl_xor(a[j], off, 64);
  }
  float dv = dinv[v];
#pragma unroll
  for (int j = 0; j < 6; ++j) a[j] *= dv;
  int f0 = lane, f1 = lane + 64;
  float o0 = b1[f0], o1 = b1[f1];
#pragma unroll
  for (int j = 0; j < 6; ++j) {
    o0 = fmaf(a[j], W1[j * HDIM + f0], o0);
    o1 = fmaf(a[j], W1[j * HDIM + f1], o1);
  }
  float s = o0 + o1, q = o0 * o0 + o1 * o1;
#pragma unroll
  for (int off = 32; off >= 1; off >>= 1) {
    s += __shfl_xor(s, off, 64);
    q += __shfl_xor(q, off, 64);
  }
  float m = s * (1.0f / HDIM);
  float var = fmaxf(q * (1.0f / HDIM) - m * m, 0.f);
  float rs = rsqrtf(var + LN_EPS);
  float y0 = fmaxf(fmaf((o0 - m) * rs, gam[f0], bet[f0]), 0.f);
  float y1 = fmaxf(fmaf((o1 - m) * rs, gam[f1], bet[f1]), 0.f);
  hout[v * HDIM + f0] = __float2half(y0 * dv);  // store h' = dinv*h
  hout[v * HDIM + f1] = __float2half(y1 * dv);
}

// ---------------- Aggregation: 4 nodes/wave, uint4 (16B)/lane, 16-deep => 64 rows/wave ----

__device__ __forceinline__ void add8(float* a, uint4 g) {
  __half2 p0 = *(__half2*)&g.x;
  __half2 p1 = *(__half2*)&g.y;
  __half2 p2 = *(__half2*)&g.z;
  __half2 p3 = *(__half2*)&g.w;
  float2 f0 = __half22float2(p0);
  float2 f1 = __half22float2(p1);
  float2 f2 = __half22float2(p2);
  float2 f3 = __half22float2(p3);
  a[0] += f0.x; a[1] += f0.y; a[2] += f1.x; a[3] += f1.y;
  a[4] += f2.x; a[5] += f2.y; a[6] += f3.x; a[7] += f3.y;
}

__global__ __launch_bounds__(256) void agg_kernel(
    const __half* __restrict__ hin, const int* __restrict__ rowptr8,
    const int* __restrict__ csr8, const float* __restrict__ dinv,
    __half* __restrict__ agg, int n) {
  int lane = threadIdx.x & 63;
  int wave = threadIdx.x >> 6;
  int hl = lane & 15;                               // lane within quarter-wave
  int v = blockIdx.x * 16 + wave * 4 + (lane >> 4); // 4 nodes per wave
  int vc = v < n ? v : n - 1;
  const uint4* h8 = (const uint4*)hin;  // 16B units; row = 16 units (256B)
  float a[8] = {0.f, 0.f, 0.f, 0.f, 0.f, 0.f, 0.f, 0.f};
  add8(a, h8[(size_t)vc * 16 + hl]);  // self-loop

  int sx = 0, ex = 0;
  if (hl < NCOH) {
    sx = rowptr8[hl * n + vc];
    ex = rowptr8[hl * n + vc + 1];
  }
  int starts[NCOH], L[NCOH + 1];
  L[0] = 0;
#pragma unroll
  for (int u = 0; u < NCOH; ++u) {
    starts[u] = __shfl(sx, u, 16);  // within own quarter
    L[u + 1] = L[u] + (__shfl(ex, u, 16) - starts[u]);
  }
  int deg = L[NCOH];
  for (int c0 = 0; c0 < deg; c0 += 16) {
    int p = c0 + hl;
    int myidx = 0;
    if (p < deg) {
      int u = 0;
#pragma unroll
      for (int t = 1; t < NCOH; ++t) u += (p >= L[t]);
      myidx = csr8[starts[u] + (p - L[u])];  // lane-parallel index preload
    }
    int cnt = min(deg - c0, 16);
    uint4 g[16];
#pragma unroll
    for (int u = 0; u < 16; ++u) {
      int s = __shfl(myidx, min(u, cnt - 1), 16);  // clamp: loads unconditional
      g[u] = h8[(size_t)s * 16 + hl];              // 1 instr = 1 full 256B row
    }
#pragma unroll
    for (int u = 0; u < 16; ++u) {
      if (u < cnt) add8(a, g[u]);  // masked add
    }
  }
  float dv = dinv[vc];
  if (v < n) {
    uint4 o;
    __half2 o0 = __floats2half2_rn(a[0] * dv, a[1] * dv);
    __half2 o1 = __floats2half2_rn(a[2] * dv, a[3] * dv);
    __half2 o2 = __floats2half2_rn(a[4] * dv, a[5] * dv);
    __half2 o3 = __floats2half2_rn(a[6] * dv, a[7] * dv);
    o.x = *(unsigned*)&o0;
    o.y = *(unsigned*)&o1;
    o.z = *(unsigned*)&o2;
    o.w = *(unsigned*)&o3;
    ((uint4*)agg)[(size_t)v * 16 + hl] = o;
  }
}

// ---------------- MFMA GEMM + LN (+ReLU -> fp16 h' | + MFMA head -> out) ----------------

__global__ __launch_bounds__(256) void mfma_gemm_kernel(
    const __half* __restrict__ aggh, const __half* __restrict__ Wt,
    const float* __restrict__ bias, const float* __restrict__ gam,
    const float* __restrict__ bet, const float* __restrict__ dinv,
    __half* __restrict__ hout,
    const __half* __restrict__ rW1t, const float* __restrict__ rb1,
    const float* __restrict__ rW2, const float* __restrict__ rb2,
    float* __restrict__ out, int n, int mode) {
  __shared__ __align__(16) __half smem[128 * 136];  // Wt staged; later aliased as tile
  int tid = threadIdx.x;
  int v0 = blockIdx.x * 64;
  int lane = tid & 63;
  int wv = tid >> 6;
  int m = lane & 15;
  int q = lane >> 4;

#pragma unroll
  for (int i = 0; i < 8; ++i) {
    int u = tid + i * 256;
    int row = u >> 4, seg = u & 15;
    *(uint4*)&smem[row * 136 + seg * 8] = *(const uint4*)&Wt[row * 128 + seg * 8];
  }

  int row = v0 + wv * 16 + m;
  int rowc = row < n ? row : n - 1;
  const __half* abase = aggh + (size_t)rowc * 128 + q * 8;
  half8 afrag[4];
#pragma unroll
  for (int kt = 0; kt < 4; ++kt) afrag[kt] = *(const half8*)(abase + kt * 32);

  __syncthreads();

  f32x4 acc[8];
#pragma unroll
  for (int c = 0; c < 8; ++c) acc[c] = (f32x4){0.f, 0.f, 0.f, 0.f};
#pragma unroll
  for (int kt = 0; kt < 4; ++kt) {
#pragma unroll
    for (int c = 0; c < 8; ++c) {
      half8 b = *(const half8*)&smem[(c * 16 + m) * 136 + kt * 32 + q * 8];
      acc[c] = __builtin_amdgcn_mfma_f32_16x16x32_f16(afrag[kt], b, acc[c], 0, 0, 0);
    }
  }

#pragma unroll
  for (int c = 0; c < 8; ++c) {
    float bcol = bias[c * 16 + m];
#pragma unroll
    for (int r = 0; r < 4; ++r) acc[c][r] += bcol;
  }
  float mean[4], rstd[4], dvr[4];
#pragma unroll
  for (int r = 0; r < 4; ++r) {
    float s = 0.f, q2 = 0.f;
#pragma unroll
    for (int c = 0; c < 8; ++c) {
      float vv = acc[c][r];
      s += vv;
      q2 += vv * vv;
    }
#pragma unroll
    for (int off = 8; off >= 1; off >>= 1) {
      s += __shfl_xor(s, off, 16);
      q2 += __shfl_xor(q2, off, 16);
    }
    float mu = s * (1.f / HDIM);
    float var = fmaxf(q2 * (1.f / HDIM) - mu * mu, 0.f);
    mean[r] = mu;
    rstd[r] = rsqrtf(var + LN_EPS);
    int vr = v0 + wv * 16 + q * 4 + r;
    dvr[r] = (mode == 1 && vr < n) ? dinv[vr] : 1.f;
  }

  __syncthreads();
  __half* tile = smem;  // 64 x 136
#pragma unroll
  for (int c = 0; c < 8; ++c) {
    float g = gam[c * 16 + m], bb = bet[c * 16 + m];
#pragma unroll
    for (int r = 0; r < 4; ++r) {
      float y = fmaf((acc[c][r] - mean[r]) * rstd[r], g, bb);
      if (mode == 1) y = fmaxf(y, 0.f) * dvr[r];
      tile[(wv * 16 + q * 4 + r) * 136 + c * 16 + m] = __float2half(y);
    }
  }
  __syncthreads();

  if (mode == 1) {
#pragma unroll
    for (int i = 0; i < 4; ++i) {
      int u = tid + i * 256;
      int r = u >> 4, seg = u & 15;
      int v = v0 + r;
      if (v < n) *(uint4*)&hout[(size_t)v * 128 + seg * 8] = *(const uint4*)&tile[r * 136 + seg * 8];
    }
    return;
  }

  f32x4 hacc[4];
#pragma unroll
  for (int c = 0; c < 4; ++c) hacc[c] = (f32x4){0.f, 0.f, 0.f, 0.f};
#pragma unroll
  for (int kt = 0; kt < 4; ++kt) {
    half8 a = *(const half8*)&tile[(wv * 16 + m) * 136 + kt * 32 + q * 8];
#pragma unroll
    for (int c = 0; c < 4; ++c) {
      half8 b = *(const half8*)&rW1t[(c * 16 + m) * 128 + kt * 32 + q * 8];
      hacc[c] = __builtin_amdgcn_mfma_f32_16x16x32_f16(a, b, hacc[c], 0, 0, 0);
    }
  }
  float p[4] = {0.f, 0.f, 0.f, 0.f};
#pragma unroll
  for (int c = 0; c < 4; ++c) {
    float rb = rb1[c * 16 + m], w2 = rW2[c * 16 + m];
#pragma unroll
    for (int r = 0; r < 4; ++r) {
      float hv = fmaxf(hacc[c][r] + rb, 0.f);
      p[r] = fmaf(hv, w2, p[r]);
    }
  }
#pragma unroll
  for (int r = 0; r < 4; ++r) {
#pragma unroll
    for (int off = 8; off >= 1; off >>= 1) p[r] += __shfl_xor(p[r], off, 16);
  }
  if (m == 0) {
    float rb2v = rb2[0];
#pragma unroll
    for (int r = 0; r < 4; ++r) {
      int v = v0 + wv * 16 + q * 4 + r;
      if (v < n) out[v] = 1.f / (1.f + expf(-(p[r] + rb2v)));
    }
  }
}

// ---------------- Launch ----------------

extern "C" void kernel_launch(void* const* d_in, const int* in_sizes, int n_in,
                              void* d_out, int out_size, void* d_ws, size_t ws_size,
                              hipStream_t stream) {
  const float* x   = (const float*)d_in[0];
  const int*  eidx = (const int*)d_in[1];
  const float* W1  = (const float*)d_in[2];
  const float* b1  = (const float*)d_in[3];
  const float* W2  = (const float*)d_in[4];
  const float* b2  = (const float*)d_in[5];
  const float* W3  = (const float*)d_in[6];
  const float* b3  = (const float*)d_in[7];
  const float* g1  = (const float*)d_in[8];
  const float* be1 = (const float*)d_in[9];
  const float* g2  = (const float*)d_in[10];
  const float* be2 = (const float*)d_in[11];
  const float* g3  = (const float*)d_in[12];
  const float* be3 = (const float*)d_in[13];
  const float* rW1 = (const float*)d_in[14];
  const float* rb1 = (const float*)d_in[15];
  const float* rW2 = (const float*)d_in[16];
  const float* rb2 = (const float*)d_in[17];

  int N = in_sizes[0] / 6;
  int E = in_sizes[1] / 2;
  const int* srcp = eidx;
  const int* dstp = eidx + E;
  float* out = (float*)d_out;

  char* p = (char*)d_ws;
  auto alloc = [&](size_t bytes) -> void* {
    void* r = (void*)p;
    p += (bytes + 255) & ~(size_t)255;
    return r;
  };
  int*    counts8  = (int*)alloc((size_t)NCOH * N * 4);
  int*    rowptr8  = (int*)alloc(((size_t)NCOH * N + 1) * 4);
  int*    cursor8  = (int*)alloc((size_t)NCOH * N * 4);
  float*  dinvp    = (float*)alloc((size_t)N * 4);
  int*    blocksum = (int*)alloc((size_t)1024 * 4);
  int*    csr8     = (int*)alloc((size_t)E * 4);
  float*  xs       = (float*)alloc((size_t)N * 8 * 4);
  __half* h16_a    = (__half*)alloc((size_t)N * HDIM * 2);
  __half* h16_b    = (__half*)alloc((size_t)N * HDIM * 2);
  __half* aggbuf   = (__half*)alloc((size_t)N * HDIM * 2);
  __half* w2t      = (__half*)alloc((size_t)HDIM * HDIM * 2);
  __half* w3t      = (__half*)alloc((size_t)HDIM * HDIM * 2);
  __half* rw1t     = (__half*)alloc((size_t)64 * HDIM * 2);

  int M8 = NCOH * N;
  int nscan8 = (M8 + 2047) / 2048;

  hipMemsetAsync(counts8, 0, (size_t)M8 * 4, stream);
  count_kernel<<<(E + 255) / 256, 256, 0, stream>>>(dstp, counts8, E, N);
  dinv_kernel<<<(N + 255) / 256, 256, 0, stream>>>(counts8, dinvp, N);
  scan_sum_kernel<<<nscan8, 256, 0, stream>>>(counts8, blocksum, M8);
  scan2_kernel<<<1, 256, 0, stream>>>(blocksum, nscan8);
  scan_emit_kernel<<<nscan8, 256, 0, stream>>>(counts8, blocksum, rowptr8, cursor8, M8, nscan8);
  fill_kernel<<<(E + 255) / 256, 256, 0, stream>>>(srcp, dstp, cursor8, csr8, E, N);
  prep_kernel<<<(N * 8 + 40960 + 255) / 256, 256, 0, stream>>>(x, dinvp, xs, W2, W3, rW1,
                                                               w2t, w3t, rw1t, N);

  int nw = (N + 3) / 4;     // layer1: one wave per node
  int nw4 = (N + 15) / 16;  // agg: four nodes per wave
  int nb = (N + 63) / 64;   // gemm: 64 rows per block
  layer1_kernel<<<nw, 256, 0, stream>>>(xs, W1, b1, g1, be1, rowptr8, csr8, dinvp, h16_a, N);
  agg_kernel<<<nw4, 256, 0, stream>>>(h16_a, rowptr8, csr8, dinvp, aggbuf, N);
  mfma_gemm_kernel<<<nb, 256, 0, stream>>>(aggbuf, w2t, b2, g2, be2, dinvp, h16_b,
                                           rw1t, rb1, rW2, rb2, out, N, 1);
  agg_kernel<<<nw4, 256, 0, stream>>>(h16_b, rowptr8, csr8, dinvp, aggbuf, N);
  mfma_gemm_kernel<<<nb, 256, 0, stream>>>(aggbuf, w3t, b3, g3, be3, dinvp, h16_b,
                                           rw1t, rb1, rW2, rb2, out, N, 2);
}

// Round 14
// 298.480 us; speedup vs baseline: 1.0207x; 1.0207x over previous
//
#include <hip/hip_runtime.h>
#include <hip/hip_fp16.h>
#include <math.h>

#define HDIM 128
#define LN_EPS 1e-5f
#define NCOH 8  // XCD cohorts (blockIdx % 8 ~ XCD round-robin heuristic; perf-only)

typedef _Float16 half8 __attribute__((ext_vector_type(8)));
typedef float f32x4 __attribute__((ext_vector_type(4)));

// h'[v] = dinv[v]*h[v]; agg[v] = dinv[v]*(sum_{s in N(v)} h'[s] + h'[v]).
// CSR is cohort-sharded x-major (kills fill write-amplification). agg: 2 nodes
// per wave, 8B/lane uint2 gathers, 16-deep pipeline (R12 form — measured best;
// R13's 4-node/16B variant was neutral: gather is at its L2/L3 service floor).

// ---------------- CSR build ----------------

__global__ void count_kernel(const int* __restrict__ dst, int* __restrict__ counts8,
                             int E, int n) {
  int e = blockIdx.x * blockDim.x + threadIdx.x;
  int x = blockIdx.x & (NCOH - 1);
  if (e < E) atomicAdd(&counts8[x * n + dst[e]], 1);
}

__global__ __launch_bounds__(256) void scan_sum_kernel(const int* __restrict__ in,
                                                       int* __restrict__ blocksum, int n) {
  int base = blockIdx.x * 2048;
  int tid = threadIdx.x;
  int sum = 0;
#pragma unroll
  for (int j = 0; j < 8; ++j) {
    int i = base + tid * 8 + j;
    if (i < n) sum += in[i];
  }
#pragma unroll
  for (int off = 32; off >= 1; off >>= 1) sum += __shfl_xor(sum, off, 64);
  __shared__ int wsum[4];
  if ((tid & 63) == 0) wsum[tid >> 6] = sum;
  __syncthreads();
  if (tid == 0) blocksum[blockIdx.x] = wsum[0] + wsum[1] + wsum[2] + wsum[3];
}

// scan_emit computes its own block prefix from the raw blocksums (nblk <= 256),
// eliminating the separate scan2 dispatch.
__global__ __launch_bounds__(256) void scan_emit_kernel(const int* __restrict__ in,
                                                        const int* __restrict__ blocksum,
                                                        int* __restrict__ rowptr8,
                                                        int* __restrict__ cursor8, int n, int nblk) {
  int tid = threadIdx.x;
  int lane = tid & 63, wid = tid >> 6;
  // Reduce raw blocksums: prefix (i < blockIdx) and total (all i).
  int bval = (tid < nblk) ? blocksum[tid] : 0;
  int pre = (tid < (int)blockIdx.x) ? bval : 0;
  int tot = bval;
#pragma unroll
  for (int off = 32; off >= 1; off >>= 1) {
    pre += __shfl_xor(pre, off, 64);
    tot += __shfl_xor(tot, off, 64);
  }
  __shared__ int wpre[4], wtot[4];
  if (lane == 0) {
    wpre[wid] = pre;
    wtot[wid] = tot;
  }
  __syncthreads();
  int sprefix = wpre[0] + wpre[1] + wpre[2] + wpre[3];
  int stotal = wtot[0] + wtot[1] + wtot[2] + wtot[3];

  int base = blockIdx.x * 2048;
  int c[8];
  int s = 0;
#pragma unroll
  for (int j = 0; j < 8; ++j) {
    int i = base + tid * 8 + j;
    c[j] = (i < n) ? in[i] : 0;
    s += c[j];
  }
  int incl = s;
#pragma unroll
  for (int off = 1; off < 64; off <<= 1) {
    int t = __shfl_up(incl, off, 64);
    if (lane >= off) incl += t;
  }
  __shared__ int wsum[4];
  if (lane == 63) wsum[wid] = incl;
  __syncthreads();
  int woff = 0;
  for (int w = 0; w < wid; ++w) woff += wsum[w];
  int p = sprefix + woff + (incl - s);
#pragma unroll
  for (int j = 0; j < 8; ++j) {
    int i = base + tid * 8 + j;
    if (i < n) {
      rowptr8[i] = p;
      cursor8[i] = p;
    }
    p += c[j];
  }
  if (blockIdx.x == nblk - 1 && tid == 255) rowptr8[n] = stotal;
}

__global__ void fill_kernel(const int* __restrict__ src, const int* __restrict__ dst,
                            int* __restrict__ cursor8, int* __restrict__ csr8, int E, int n) {
  int e = blockIdx.x * blockDim.x + threadIdx.x;
  int x = blockIdx.x & (NCOH - 1);
  if (e < E) {
    int pos = atomicAdd(&cursor8[x * n + dst[e]], 1);
    csr8[pos] = src[e];  // cohort-owned contiguous region -> XCD-local L2 lines
  }
}

// ---------------- Prep: dinv (from counts8, width-8 shfl), xs (stride 8) = dinv*x,
//                  fp16-transposed weights — all fused in one dispatch ----------------

__global__ void prep_kernel(const float* __restrict__ x, const int* __restrict__ counts8,
                            float* __restrict__ dinv, float* __restrict__ xs,
                            const float* __restrict__ W2, const float* __restrict__ W3,
                            const float* __restrict__ rW1, __half* __restrict__ w2t,
                            __half* __restrict__ w3t, __half* __restrict__ rw1t, int n) {
  int idx = blockIdx.x * 256 + threadIdx.x;
  int nx = n * 8;
  if (idx < nx) {
    int vv = idx >> 3, j = idx & 7;  // 8 lanes per node (group-aligned within wave)
    int c = counts8[j * n + vv];
    int s = c;
    s += __shfl_xor(s, 1, 8);
    s += __shfl_xor(s, 2, 8);
    s += __shfl_xor(s, 4, 8);
    float dv = rsqrtf((float)(s + 1));  // +1 self-loop
    xs[idx] = (j < 6) ? x[vv * 6 + j] * dv : 0.f;
    if (j == 7) dinv[vv] = dv;
    return;
  }
  int i = idx - nx;
  if (i < 16384) {
    int nn = i >> 7, k = i & 127;
    w2t[i] = __float2half(W2[k * 128 + nn]);
  } else if (i < 32768) {
    int j = i - 16384;
    int nn = j >> 7, k = j & 127;
    w3t[j] = __float2half(W3[k * 128 + nn]);
  } else if (i < 40960) {
    int j = i - 32768;
    int nn = j >> 7, k = j & 127;
    rw1t[j] = __float2half(rW1[k * 64 + nn]);
  }
}

// ---------------- Layer 1: one wave/node; lane-owned edges, 2x float4 loads ----------

__global__ __launch_bounds__(256) void layer1_kernel(
    const float* __restrict__ xs, const float* __restrict__ W1,
    const float* __restrict__ b1, const float* __restrict__ gam,
    const float* __restrict__ bet, const int* __restrict__ rowptr8,
    const int* __restrict__ csr8, const float* __restrict__ dinv,
    __half* __restrict__ hout, int n) {
  int v = blockIdx.x * 4 + (threadIdx.x >> 6);
  if (v >= n) return;
  int lane = threadIdx.x & 63;
  int sx = 0, ex = 0;
  if (lane < NCOH) {
    sx = rowptr8[lane * n + v];
    ex = rowptr8[lane * n + v + 1];
  }
  int starts[NCOH], L[NCOH + 1];
  L[0] = 0;
#pragma unroll
  for (int u = 0; u < NCOH; ++u) {
    starts[u] = __shfl(sx, u, 64);
    L[u + 1] = L[u] + (__shfl(ex, u, 64) - starts[u]);
  }
  int deg = L[NCOH];
  float a[6] = {0.f, 0.f, 0.f, 0.f, 0.f, 0.f};
  for (int c0 = 0; c0 < deg; c0 += 64) {
    int p = c0 + lane;
    if (p < deg) {
      int u = 0;
#pragma unroll
      for (int t = 1; t < NCOH; ++t) u += (p >= L[t]);
      int s = csr8[starts[u] + (p - L[u])];  // lane-owned edge
      float4 x0 = *(const float4*)&xs[s * 8];
      float4 x1 = *(const float4*)&xs[s * 8 + 4];
      a[0] += x0.x; a[1] += x0.y; a[2] += x0.z;
      a[3] += x0.w; a[4] += x1.x; a[5] += x1.y;
    }
  }
  if (lane == 0) {
#pragma unroll
    for (int j = 0; j < 6; ++j) a[j] += xs[v * 8 + j];  // self-loop
  }
#pragma unroll
  for (int off = 32; off >= 1; off >>= 1) {
#pragma unroll
    for (int j = 0; j < 6; ++j) a[j] += __shfl_xor(a[j], off, 64);
  }
  float dv = dinv[v];
#pragma unroll
  for (int j = 0; j < 6; ++j) a[j] *= dv;
  int f0 = lane, f1 = lane + 64;
  float o0 = b1[f0], o1 = b1[f1];
#pragma unroll
  for (int j = 0; j < 6; ++j) {
    o0 = fmaf(a[j], W1[j * HDIM + f0], o0);
    o1 = fmaf(a[j], W1[j * HDIM + f1], o1);
  }
  float s = o0 + o1, q = o0 * o0 + o1 * o1;
#pragma unroll
  for (int off = 32; off >= 1; off >>= 1) {
    s += __shfl_xor(s, off, 64);
    q += __shfl_xor(q, off, 64);
  }
  float m = s * (1.0f / HDIM);
  float var = fmaxf(q * (1.0f / HDIM) - m * m, 0.f);
  float rs = rsqrtf(var + LN_EPS);
  float y0 = fmaxf(fmaf((o0 - m) * rs, gam[f0], bet[f0]), 0.f);
  float y1 = fmaxf(fmaf((o1 - m) * rs, gam[f1], bet[f1]), 0.f);
  hout[v * HDIM + f0] = __float2half(y0 * dv);  // store h' = dinv*h
  hout[v * HDIM + f1] = __float2half(y1 * dv);
}

// ---------------- Aggregation: 2 nodes/wave, uint2 (8B)/lane, 16-deep => 32 rows in flight ----

__device__ __forceinline__ void add4(float& a0, float& a1, float& a2, float& a3, uint2 g) {
  __half2 lo = *(__half2*)&g.x;
  __half2 hi = *(__half2*)&g.y;
  float2 f0 = __half22float2(lo);
  float2 f1 = __half22float2(hi);
  a0 += f0.x; a1 += f0.y; a2 += f1.x; a3 += f1.y;
}

__global__ __launch_bounds__(256) void agg_kernel(
    const __half* __restrict__ hin, const int* __restrict__ rowptr8,
    const int* __restrict__ csr8, const float* __restrict__ dinv,
    __half* __restrict__ agg, int n) {
  int lane = threadIdx.x & 63;
  int wave = threadIdx.x >> 6;
  int hl = lane & 31;                              // lane within half-wave
  int v = blockIdx.x * 8 + wave * 2 + (lane >> 5); // 2 nodes per wave
  int vc = v < n ? v : n - 1;
  const uint2* h4 = (const uint2*)hin;  // 8B units; row = 32 units (256B)
  uint2 self = h4[(size_t)vc * 32 + hl];
  float a0 = 0.f, a1 = 0.f, a2 = 0.f, a3 = 0.f;
  add4(a0, a1, a2, a3, self);  // self-loop

  int sx = 0, ex = 0;
  if (hl < NCOH) {
    sx = rowptr8[hl * n + vc];
    ex = rowptr8[hl * n + vc + 1];
  }
  int starts[NCOH], L[NCOH + 1];
  L[0] = 0;
#pragma unroll
  for (int u = 0; u < NCOH; ++u) {
    starts[u] = __shfl(sx, u, 32);  // within own half
    L[u + 1] = L[u] + (__shfl(ex, u, 32) - starts[u]);
  }
  int deg = L[NCOH];
  for (int c0 = 0; c0 < deg; c0 += 32) {
    int p = c0 + hl;
    int myidx = 0;
    if (p < deg) {
      int u = 0;
#pragma unroll
      for (int t = 1; t < NCOH; ++t) u += (p >= L[t]);
      myidx = csr8[starts[u] + (p - L[u])];  // lane-parallel index preload
    }
    int cnt = min(deg - c0, 32);
    for (int j = 0; j < cnt; j += 16) {
      uint2 g[16];
#pragma unroll
      for (int u = 0; u < 16; ++u) {
        int s = __shfl(myidx, min(j + u, cnt - 1), 32);  // clamp: loads unconditional
        g[u] = h4[(size_t)s * 32 + hl];
      }
#pragma unroll
      for (int u = 0; u < 16; ++u) {
        if (j + u < cnt) add4(a0, a1, a2, a3, g[u]);  // masked add
      }
    }
  }
  float dv = dinv[vc];
  if (v < n) {
    uint2 outp;
    __half2 lo = __floats2half2_rn(a0 * dv, a1 * dv);
    __half2 hi = __floats2half2_rn(a2 * dv, a3 * dv);
    outp.x = *(unsigned*)&lo;
    outp.y = *(unsigned*)&hi;
    ((uint2*)agg)[(size_t)v * 32 + hl] = outp;
  }
}

// ---------------- MFMA GEMM + LN (+ReLU -> fp16 h' | + MFMA head -> out) ----------------

__global__ __launch_bounds__(256) void mfma_gemm_kernel(
    const __half* __restrict__ aggh, const __half* __restrict__ Wt,
    const float* __restrict__ bias, const float* __restrict__ gam,
    const float* __restrict__ bet, const float* __restrict__ dinv,
    __half* __restrict__ hout,
    const __half* __restrict__ rW1t, const float* __restrict__ rb1,
    const float* __restrict__ rW2, const float* __restrict__ rb2,
    float* __restrict__ out, int n, int mode) {
  __shared__ __align__(16) __half smem[128 * 136];  // Wt staged; later aliased as tile
  int tid = threadIdx.x;
  int v0 = blockIdx.x * 64;
  int lane = tid & 63;
  int wv = tid >> 6;
  int m = lane & 15;
  int q = lane >> 4;

#pragma unroll
  for (int i = 0; i < 8; ++i) {
    int u = tid + i * 256;
    int row = u >> 4, seg = u & 15;
    *(uint4*)&smem[row * 136 + seg * 8] = *(const uint4*)&Wt[row * 128 + seg * 8];
  }

  int row = v0 + wv * 16 + m;
  int rowc = row < n ? row : n - 1;
  const __half* abase = aggh + (size_t)rowc * 128 + q * 8;
  half8 afrag[4];
#pragma unroll
  for (int kt = 0; kt < 4; ++kt) afrag[kt] = *(const half8*)(abase + kt * 32);

  __syncthreads();

  f32x4 acc[8];
#pragma unroll
  for (int c = 0; c < 8; ++c) acc[c] = (f32x4){0.f, 0.f, 0.f, 0.f};
#pragma unroll
  for (int kt = 0; kt < 4; ++kt) {
#pragma unroll
    for (int c = 0; c < 8; ++c) {
      half8 b = *(const half8*)&smem[(c * 16 + m) * 136 + kt * 32 + q * 8];
      acc[c] = __builtin_amdgcn_mfma_f32_16x16x32_f16(afrag[kt], b, acc[c], 0, 0, 0);
    }
  }

#pragma unroll
  for (int c = 0; c < 8; ++c) {
    float bcol = bias[c * 16 + m];
#pragma unroll
    for (int r = 0; r < 4; ++r) acc[c][r] += bcol;
  }
  float mean[4], rstd[4], dvr[4];
#pragma unroll
  for (int r = 0; r < 4; ++r) {
    float s = 0.f, q2 = 0.f;
#pragma unroll
    for (int c = 0; c < 8; ++c) {
      float vv = acc[c][r];
      s += vv;
      q2 += vv * vv;
    }
#pragma unroll
    for (int off = 8; off >= 1; off >>= 1) {
      s += __shfl_xor(s, off, 16);
      q2 += __shfl_xor(q2, off, 16);
    }
    float mu = s * (1.f / HDIM);
    float var = fmaxf(q2 * (1.f / HDIM) - mu * mu, 0.f);
    mean[r] = mu;
    rstd[r] = rsqrtf(var + LN_EPS);
    int vr = v0 + wv * 16 + q * 4 + r;
    dvr[r] = (mode == 1 && vr < n) ? dinv[vr] : 1.f;
  }

  __syncthreads();
  __half* tile = smem;  // 64 x 136
#pragma unroll
  for (int c = 0; c < 8; ++c) {
    float g = gam[c * 16 + m], bb = bet[c * 16 + m];
#pragma unroll
    for (int r = 0; r < 4; ++r) {
      float y = fmaf((acc[c][r] - mean[r]) * rstd[r], g, bb);
      if (mode == 1) y = fmaxf(y, 0.f) * dvr[r];
      tile[(wv * 16 + q * 4 + r) * 136 + c * 16 + m] = __float2half(y);
    }
  }
  __syncthreads();

  if (mode == 1) {
#pragma unroll
    for (int i = 0; i < 4; ++i) {
      int u = tid + i * 256;
      int r = u >> 4, seg = u & 15;
      int v = v0 + r;
      if (v < n) *(uint4*)&hout[(size_t)v * 128 + seg * 8] = *(const uint4*)&tile[r * 136 + seg * 8];
    }
    return;
  }

  f32x4 hacc[4];
#pragma unroll
  for (int c = 0; c < 4; ++c) hacc[c] = (f32x4){0.f, 0.f, 0.f, 0.f};
#pragma unroll
  for (int kt = 0; kt < 4; ++kt) {
    half8 a = *(const half8*)&tile[(wv * 16 + m) * 136 + kt * 32 + q * 8];
#pragma unroll
    for (int c = 0; c < 4; ++c) {
      half8 b = *(const half8*)&rW1t[(c * 16 + m) * 128 + kt * 32 + q * 8];
      hacc[c] = __builtin_amdgcn_mfma_f32_16x16x32_f16(a, b, hacc[c], 0, 0, 0);
    }
  }
  float p[4] = {0.f, 0.f, 0.f, 0.f};
#pragma unroll
  for (int c = 0; c < 4; ++c) {
    float rb = rb1[c * 16 + m], w2 = rW2[c * 16 + m];
#pragma unroll
    for (int r = 0; r < 4; ++r) {
      float hv = fmaxf(hacc[c][r] + rb, 0.f);
      p[r] = fmaf(hv, w2, p[r]);
    }
  }
#pragma unroll
  for (int r = 0; r < 4; ++r) {
#pragma unroll
    for (int off = 8; off >= 1; off >>= 1) p[r] += __shfl_xor(p[r], off, 16);
  }
  if (m == 0) {
    float rb2v = rb2[0];
#pragma unroll
    for (int r = 0; r < 4; ++r) {
      int v = v0 + wv * 16 + q * 4 + r;
      if (v < n) out[v] = 1.f / (1.f + expf(-(p[r] + rb2v)));
    }
  }
}

// ---------------- Launch ----------------

extern "C" void kernel_launch(void* const* d_in, const int* in_sizes, int n_in,
                              void* d_out, int out_size, void* d_ws, size_t ws_size,
                              hipStream_t stream) {
  const float* x   = (const float*)d_in[0];
  const int*  eidx = (const int*)d_in[1];
  const float* W1  = (const float*)d_in[2];
  const float* b1  = (const float*)d_in[3];
  const float* W2  = (const float*)d_in[4];
  const float* b2  = (const float*)d_in[5];
  const float* W3  = (const float*)d_in[6];
  const float* b3  = (const float*)d_in[7];
  const float* g1  = (const float*)d_in[8];
  const float* be1 = (const float*)d_in[9];
  const float* g2  = (const float*)d_in[10];
  const float* be2 = (const float*)d_in[11];
  const float* g3  = (const float*)d_in[12];
  const float* be3 = (const float*)d_in[13];
  const float* rW1 = (const float*)d_in[14];
  const float* rb1 = (const float*)d_in[15];
  const float* rW2 = (const float*)d_in[16];
  const float* rb2 = (const float*)d_in[17];

  int N = in_sizes[0] / 6;
  int E = in_sizes[1] / 2;
  const int* srcp = eidx;
  const int* dstp = eidx + E;
  float* out = (float*)d_out;

  char* p = (char*)d_ws;
  auto alloc = [&](size_t bytes) -> void* {
    void* r = (void*)p;
    p += (bytes + 255) & ~(size_t)255;
    return r;
  };
  int*    counts8  = (int*)alloc((size_t)NCOH * N * 4);
  int*    rowptr8  = (int*)alloc(((size_t)NCOH * N + 1) * 4);
  int*    cursor8  = (int*)alloc((size_t)NCOH * N * 4);
  float*  dinvp    = (float*)alloc((size_t)N * 4);
  int*    blocksum = (int*)alloc((size_t)1024 * 4);
  int*    csr8     = (int*)alloc((size_t)E * 4);
  float*  xs       = (float*)alloc((size_t)N * 8 * 4);
  __half* h16_a    = (__half*)alloc((size_t)N * HDIM * 2);
  __half* h16_b    = (__half*)alloc((size_t)N * HDIM * 2);
  __half* aggbuf   = (__half*)alloc((size_t)N * HDIM * 2);
  __half* w2t      = (__half*)alloc((size_t)HDIM * HDIM * 2);
  __half* w3t      = (__half*)alloc((size_t)HDIM * HDIM * 2);
  __half* rw1t     = (__half*)alloc((size_t)64 * HDIM * 2);

  int M8 = NCOH * N;
  int nscan8 = (M8 + 2047) / 2048;  // 196 blocks for N=50k (<=256 supported)

  hipMemsetAsync(counts8, 0, (size_t)M8 * 4, stream);
  count_kernel<<<(E + 255) / 256, 256, 0, stream>>>(dstp, counts8, E, N);
  scan_sum_kernel<<<nscan8, 256, 0, stream>>>(counts8, blocksum, M8);
  scan_emit_kernel<<<nscan8, 256, 0, stream>>>(counts8, blocksum, rowptr8, cursor8, M8, nscan8);
  fill_kernel<<<(E + 255) / 256, 256, 0, stream>>>(srcp, dstp, cursor8, csr8, E, N);
  prep_kernel<<<(N * 8 + 40960 + 255) / 256, 256, 0, stream>>>(x, counts8, dinvp, xs,
                                                               W2, W3, rW1, w2t, w3t, rw1t, N);

  int nw = (N + 3) / 4;    // layer1: one wave per node
  int nw2 = (N + 7) / 8;   // agg: two nodes per wave
  int nb = (N + 63) / 64;  // gemm: 64 rows per block
  layer1_kernel<<<nw, 256, 0, stream>>>(xs, W1, b1, g1, be1, rowptr8, csr8, dinvp, h16_a, N);
  agg_kernel<<<nw2, 256, 0, stream>>>(h16_a, rowptr8, csr8, dinvp, aggbuf, N);
  mfma_gemm_kernel<<<nb, 256, 0, stream>>>(aggbuf, w2t, b2, g2, be2, dinvp, h16_b,
                                           rw1t, rb1, rW2, rb2, out, N, 1);
  agg_kernel<<<nw2, 256, 0, stream>>>(h16_b, rowptr8, csr8, dinvp, aggbuf, N);
  mfma_gemm_kernel<<<nb, 256, 0, stream>>>(aggbuf, w3t, b3, g3, be3, dinvp, h16_b,
                                           rw1t, rb1, rW2, rb2, out, N, 2);
}